// Round 14
// baseline (271.917 us; speedup 1.0000x reference)
//
#include <hip/hip_runtime.h>
#include <hip/hip_bf16.h>

#define N_NODES 10000
#define N_EDGES 320000
#define HDIM    256
#define NCLS    40
#define WTOT    273448
#define WQUADS  68362   // WTOT/4 exactly

typedef __attribute__((ext_vector_type(8))) short short8;
typedef __attribute__((ext_vector_type(4))) float floatx4;
typedef __attribute__((ext_vector_type(4))) int intx4;
typedef unsigned long long ull;
typedef unsigned short ushort;

__device__ __forceinline__ float bf2f(ushort u) {
    union { unsigned int i; float f; } v; v.i = ((unsigned int)u) << 16; return v.f;
}
__device__ __forceinline__ ushort f2bf(float f) {
    __hip_bfloat16 h = __float2bfloat16(f);
    return *reinterpret_cast<ushort*>(&h);
}

// Per-block dtype detection: flags computed from first 64 elements.
__device__ __forceinline__ void detect_flags(const void* x, const void* ei,
                                             int* sflags) {
    const int tid = threadIdx.x;
    if (tid < 64) {
        const ushort* u = (const ushort*)x;
        int e = (u[2 * tid] >> 7) & 0xFF;
        ull badmask = __ballot(e < 100 || e > 140);
        const int* ii = (const int*)ei;
        ull oddnz = __ballot(ii[2 * tid + 1] != 0);
        if (tid == 0) {
            sflags[0] = (__popcll(badmask) >= 8) ? 1 : 0;
            sflags[1] = (oddnz == 0) ? 1 : 0;
        }
    }
    __syncthreads();
}

// ---------------- fused prep: detect + x/W convert + edge decode + count ----------------
// Weight conversion vectorized 4-wide: every tensor size and offset is a
// multiple of 4, so groups of 4 consecutive elements never straddle a tensor
// boundary. 1069 scalar blocks -> 268 vector blocks.

struct PrepArgs {
    const void* x;
    const void* ei;
    const void* wsrc[10];
    ushort* wdst[10];
    int woffs[11];
    ushort* xb;
    int* src32;
    int* dst32;
    int* cnt;       // pre-zeroed by hipMemsetAsync
    ushort* tbuf;
    ushort* hbuf;
    int* flags;
};

#define PREP_XB 2500
#define PREP_WB 268
#define PREP_EB 1250
#define PREP_TOTAL (PREP_XB + PREP_WB + PREP_EB + 1)

__global__ __launch_bounds__(256)
void prep_kernel(PrepArgs a) {
    __shared__ int sflags[2];
    detect_flags(a.x, a.ei, sflags);
    const int f32 = sflags[0];
    const int b = blockIdx.x;

    if (b < PREP_XB) {
        int i4 = b * 256 + threadIdx.x;   // 2500*256 == N*H/4 exactly
        if (f32) {
            float4 v = ((const float4*)a.x)[i4];
            ull p = (ull)f2bf(v.x) | ((ull)f2bf(v.y) << 16) |
                    ((ull)f2bf(v.z) << 32) | ((ull)f2bf(v.w) << 48);
            ((ull*)a.xb)[i4] = p;
        } else {
            ((ull*)a.xb)[i4] = ((const ull*)a.x)[i4];
        }
    } else if (b < PREP_XB + PREP_WB) {
        int i = (b - PREP_XB) * 256 + threadIdx.x;
        if (i < WQUADS) {
            int i4 = i * 4;
            int t = 0;
#pragma unroll
            for (int k = 1; k < 10; ++k) t += (i4 >= a.woffs[k]);
            int local = i4 - a.woffs[t];     // %4 == 0
            ull p;
            if (f32) {
                float4 v = *(const float4*)((const float*)a.wsrc[t] + local);
                p = (ull)f2bf(v.x) | ((ull)f2bf(v.y) << 16) |
                    ((ull)f2bf(v.z) << 32) | ((ull)f2bf(v.w) << 48);
            } else {
                p = *(const ull*)((const ushort*)a.wsrc[t] + local);
            }
            *(ull*)(a.wdst[t] + local) = p;
        }
    } else if (b < PREP_XB + PREP_WB + PREP_EB) {
        int e = (b - PREP_XB - PREP_WB) * 256 + threadIdx.x;  // exact
        const int* ii = (const int*)a.ei;
        int s, d;
        if (sflags[1]) { s = ii[2 * e]; d = ii[2 * (N_EDGES + e)]; }
        else           { s = ii[e];     d = ii[N_EDGES + e]; }
        s = ((unsigned)s < N_NODES) ? s : 0;
        d = ((unsigned)d < N_NODES) ? d : 0;
        a.src32[e] = s;
        a.dst32[e] = d;
        atomicAdd(&a.cnt[d], 1);
    } else {
        int t = threadIdx.x;
        if (t < 64)       ((ull*)(a.tbuf + (size_t)N_NODES * 256))[t] = 0;
        else if (t < 128) ((ull*)(a.hbuf + (size_t)N_NODES * 256))[t - 64] = 0;
        if (t == 0) { a.flags[0] = sflags[0]; a.flags[1] = sflags[1]; }
    }
}

// ---------------- scan + dinv (1 block, wave-shuffle scan, 2 barriers) ----------------

__global__ __launch_bounds__(1024)
void scan_dinv_kernel(const int* __restrict__ cnt, int* __restrict__ offs,
                      int* __restrict__ woff, float* __restrict__ dinv) {
    __shared__ int wsum[16];
    const int t = threadIdx.x;
    const int lane = t & 63;
    const int wv = t >> 6;
    const int base = t * 10;            // 1024*10 = 10240 >= N_NODES

    int c[10];
    int s = 0;
#pragma unroll
    for (int j = 0; j < 10; ++j) {
        int i = base + j;
        c[j] = (i < N_NODES) ? cnt[i] : 0;
        s += c[j];
    }

    int inc = s;
#pragma unroll
    for (int o = 1; o < 64; o <<= 1) {
        int v = __shfl_up(inc, o);
        if (lane >= o) inc += v;
    }
    if (lane == 63) wsum[wv] = inc;
    __syncthreads();

    if (wv == 0 && lane < 16) {
        int w = wsum[lane];
        int wi = w;
#pragma unroll
        for (int o = 1; o < 16; o <<= 1) {
            int v = __shfl_up(wi, o);
            if (lane >= o) wi += v;
        }
        wsum[lane] = wi - w;
    }
    __syncthreads();

    int run = wsum[wv] + (inc - s);
#pragma unroll
    for (int j = 0; j < 10; ++j) {
        int i = base + j;
        if (i < N_NODES) {
            offs[i] = run;
            woff[i] = run;
            dinv[i] = rsqrtf((float)c[j] + 1.0f);
            run += c[j];
        }
    }
}

// ---------------- fused CSR-fill + GEMM layer 1 ----------------

#define FILL_BLKS 1250
#define GEMM1_YT  78
#define FG_TOTAL  (FILL_BLKS + 8 * GEMM1_YT)

__global__ __launch_bounds__(256)
void fillgemm_kernel(const int* __restrict__ src, const int* __restrict__ dst,
                     int* __restrict__ woff, int* __restrict__ csr,
                     const ushort* __restrict__ A, const ushort* __restrict__ W,
                     const float* __restrict__ dinv, ushort* __restrict__ T) {
    const int b = blockIdx.x;
    if (b < FILL_BLKS) {
        int e = b * 256 + threadIdx.x;
        int d = dst[e];
        int p = atomicAdd(&woff[d], 1);
        csr[p] = src[e];
        return;
    }
    const int g = b - FILL_BLKS;
    const int lane = threadIdx.x & 63;
    const int wave = threadIdx.x >> 6;
    const int m = lane & 15;
    const int quad = lane >> 4;
    const int c0 = (g & 7) * 32;
    const int by = g >> 3;

    short8 bfrag[2][8];
#pragma unroll
    for (int t = 0; t < 2; ++t)
#pragma unroll
        for (int s = 0; s < 8; ++s)
#pragma unroll
            for (int j = 0; j < 8; ++j)
                bfrag[t][s][j] = (short)W[(size_t)(s * 32 + quad * 8 + j) * 256 + c0 + t * 16 + m];

    const int step = GEMM1_YT * 4;
    for (int rt = by * 4 + wave; rt < N_NODES / 16; rt += step) {
        const int r0 = rt * 16;
        floatx4 acc0 = {0.f, 0.f, 0.f, 0.f};
        floatx4 acc1 = {0.f, 0.f, 0.f, 0.f};
        const ushort* arow = A + (size_t)(r0 + m) * 256 + quad * 8;
#pragma unroll
        for (int s = 0; s < 8; ++s) {
            short8 af = *(const short8*)(arow + s * 32);
            acc0 = __builtin_amdgcn_mfma_f32_16x16x32_bf16(af, bfrag[0][s], acc0, 0, 0, 0);
            acc1 = __builtin_amdgcn_mfma_f32_16x16x32_bf16(af, bfrag[1][s], acc1, 0, 0, 0);
        }
#pragma unroll
        for (int r = 0; r < 4; ++r) {
            int row = r0 + quad * 4 + r;
            float di = dinv[row];
            T[(size_t)row * 256 + c0 + m]      = f2bf(acc0[r] * di);
            T[(size_t)row * 256 + c0 + 16 + m] = f2bf(acc1[r] * di);
        }
    }
}

// ---------------- GEMM 256-wide (layers 2-4), grid (8, 78) ----------------

__global__ __launch_bounds__(256)
void gemm256_kernel(const ushort* __restrict__ A, const ushort* __restrict__ W,
                    const float* __restrict__ dinv, ushort* __restrict__ T) {
    const int lane = threadIdx.x & 63;
    const int wave = threadIdx.x >> 6;
    const int m = lane & 15;
    const int quad = lane >> 4;
    const int c0 = blockIdx.x * 32;

    short8 bfrag[2][8];
#pragma unroll
    for (int t = 0; t < 2; ++t)
#pragma unroll
        for (int s = 0; s < 8; ++s)
#pragma unroll
            for (int j = 0; j < 8; ++j)
                bfrag[t][s][j] = (short)W[(size_t)(s * 32 + quad * 8 + j) * 256 + c0 + t * 16 + m];

    const int step = gridDim.y * 4;
    for (int rt = blockIdx.y * 4 + wave; rt < N_NODES / 16; rt += step) {
        const int r0 = rt * 16;
        floatx4 acc0 = {0.f, 0.f, 0.f, 0.f};
        floatx4 acc1 = {0.f, 0.f, 0.f, 0.f};
        const ushort* arow = A + (size_t)(r0 + m) * 256 + quad * 8;
#pragma unroll
        for (int s = 0; s < 8; ++s) {
            short8 af = *(const short8*)(arow + s * 32);
            acc0 = __builtin_amdgcn_mfma_f32_16x16x32_bf16(af, bfrag[0][s], acc0, 0, 0, 0);
            acc1 = __builtin_amdgcn_mfma_f32_16x16x32_bf16(af, bfrag[1][s], acc1, 0, 0, 0);
        }
#pragma unroll
        for (int r = 0; r < 4; ++r) {
            int row = r0 + quad * 4 + r;
            float di = dinv[row];
            T[(size_t)row * 256 + c0 + m]      = f2bf(acc0[r] * di);
            T[(size_t)row * 256 + c0 + 16 + m] = f2bf(acc1[r] * di);
        }
    }
}

// ---------------- GEMM 40-wide -> fp32 t5, grid (3, 80) ----------------

__global__ __launch_bounds__(256)
void gemm40_kernel(const ushort* __restrict__ A, const ushort* __restrict__ W,
                   const float* __restrict__ dinv, float* __restrict__ T) {
    const int lane = threadIdx.x & 63;
    const int wave = threadIdx.x >> 6;
    const int m = lane & 15;
    const int quad = lane >> 4;
    const int col = blockIdx.x * 16 + m;
    const bool colok = col < NCLS;

    short8 bfrag[8];
#pragma unroll
    for (int s = 0; s < 8; ++s)
#pragma unroll
        for (int j = 0; j < 8; ++j)
            bfrag[s][j] = colok ? (short)W[(size_t)(s * 32 + quad * 8 + j) * NCLS + col] : (short)0;

    const int step = gridDim.y * 4;
    for (int rt = blockIdx.y * 4 + wave; rt < N_NODES / 16; rt += step) {
        const int r0 = rt * 16;
        floatx4 acc = {0.f, 0.f, 0.f, 0.f};
        const ushort* arow = A + (size_t)(r0 + m) * 256 + quad * 8;
#pragma unroll
        for (int s = 0; s < 8; ++s) {
            short8 af = *(const short8*)(arow + s * 32);
            acc = __builtin_amdgcn_mfma_f32_16x16x32_bf16(af, bfrag[s], acc, 0, 0, 0);
        }
        if (colok) {
#pragma unroll
            for (int r = 0; r < 4; ++r) {
                int row = r0 + quad * 4 + r;
                T[(size_t)row * NCLS + col] = acc[r] * dinv[row];
            }
        }
    }
}

// ---------------- Aggregation 256-wide: ordered column halves + nt stores ----------------
// Blocks 0..2499 process cols 0..127 for all nodes, blocks 2500..4999 cols
// 128..255. Dispatch-order locality: the first ~2048 co-resident blocks all
// touch the same 2.56MB T-slice (+1.3MB csr) -> fits each XCD's 4MB L2.
// Non-temporal H stores keep the 5MB write stream from evicting the gather
// set. Quarter-wave (16 lanes x 16B) per neighbor, 4 neighbors in flight.

__device__ __forceinline__ void accum16(float* acc, intx4 r) {
    int d[4] = {r.x, r.y, r.z, r.w};
#pragma unroll
    for (int k = 0; k < 4; ++k) {
        union { int i; float f; } lo, hi;
        lo.i = d[k] << 16;
        hi.i = d[k] & 0xffff0000;
        acc[2 * k]     += lo.f;
        acc[2 * k + 1] += hi.f;
    }
}

#define AGG_BLKS 5000

__global__ __launch_bounds__(256, 4)
void agg256_kernel(const ushort* __restrict__ T,
                   const int* __restrict__ csr, const int* __restrict__ offs,
                   const int* __restrict__ cnt, const float* __restrict__ dinv,
                   const ushort* __restrict__ bias,
                   ushort* __restrict__ H) {
    const int bid = blockIdx.x;
    const int h = (bid >= 2500) ? 1 : 0;
    const int local = h ? (bid - 2500) : bid;       // 0..2499
    const int wave = threadIdx.x >> 6;
    const int node = local * 4 + wave;              // 0..9999
    const int lane = threadIdx.x & 63;
    const int quarter = lane >> 4;
    const int q = lane & 15;
    const int cbase = h * 128 + q * 8;              // ushort offset within row

    const int start = offs[node];
    const int count = cnt[node];
    const float di = dinv[node];

    float acc[8];
    {
        int sinit = quarter ? N_NODES : node;       // self row once (quarter 0)
        intx4 r = *(const intx4*)(T + (size_t)sinit * 256 + cbase);
#pragma unroll
        for (int k = 0; k < 4; ++k) {
            union { int i; float f; } lo, hi;
            int d = r[k];
            lo.i = d << 16; hi.i = d & 0xffff0000;
            acc[2 * k] = lo.f; acc[2 * k + 1] = hi.f;
        }
    }

    for (int bj = 0; bj < count; bj += 64) {
        int mrem = count - bj;
        int mm = mrem < 64 ? mrem : 64;
        int idxv = (lane < mm) ? csr[start + bj + lane] : N_NODES;
        int j2 = 0;
        for (; j2 + 16 <= mm; j2 += 16) {
            int s0 = __shfl(idxv, j2 + 0  + quarter);
            int s1 = __shfl(idxv, j2 + 4  + quarter);
            int s2 = __shfl(idxv, j2 + 8  + quarter);
            int s3 = __shfl(idxv, j2 + 12 + quarter);
            intx4 r0 = *(const intx4*)(T + (size_t)s0 * 256 + cbase);
            intx4 r1 = *(const intx4*)(T + (size_t)s1 * 256 + cbase);
            intx4 r2 = *(const intx4*)(T + (size_t)s2 * 256 + cbase);
            intx4 r3 = *(const intx4*)(T + (size_t)s3 * 256 + cbase);
            accum16(acc, r0); accum16(acc, r1); accum16(acc, r2); accum16(acc, r3);
        }
        for (; j2 < mm; j2 += 4) {
            int s = __shfl(idxv, j2 + quarter);     // sentinel-padded beyond mm
            intx4 r = *(const intx4*)(T + (size_t)s * 256 + cbase);
            accum16(acc, r);
        }
    }

#pragma unroll
    for (int i = 0; i < 8; ++i) {
        acc[i] += __shfl_xor(acc[i], 32);
        acc[i] += __shfl_xor(acc[i], 16);
    }

    if (quarter == 0) {
        intx4 bv = *(const intx4*)(bias + cbase);
        intx4 ov;
#pragma unroll
        for (int k = 0; k < 4; ++k) {
            union { int i; float f; } lo, hi;
            int d = bv[k];
            lo.i = d << 16; hi.i = d & 0xffff0000;
            float v0 = fmaxf(acc[2 * k] * di + lo.f, 0.f);
            float v1 = fmaxf(acc[2 * k + 1] * di + hi.f, 0.f);
            ov[k] = (int)f2bf(v0) | ((int)f2bf(v1) << 16);
        }
        __builtin_nontemporal_store(ov, (intx4*)(H + (size_t)node * 256 + cbase));
    }
}

// ---------------- Aggregation 40-wide + log_softmax + output ----------------

__global__ __launch_bounds__(256)
void aggsoft_kernel(const float* __restrict__ T,
                    const int* __restrict__ csr, const int* __restrict__ offs,
                    const int* __restrict__ cnt, const float* __restrict__ dinv,
                    const ushort* __restrict__ bias,
                    void* __restrict__ out, const int* __restrict__ flags) {
    const int node = blockIdx.x * 4 + (threadIdx.x >> 6);
    const int lane = threadIdx.x & 63;
    const int start = offs[node];
    const int count = cnt[node];
    const float di = dinv[node];

    float acc = (lane < NCLS) ? T[(size_t)node * NCLS + lane] : 0.f;
    for (int bj = 0; bj < count; bj += 64) {
        int mrem = count - bj;
        int mm = mrem < 64 ? mrem : 64;
        int idxv = (lane < mm) ? csr[start + bj + lane] : 0;
        int jj = 0;
        for (; jj + 4 <= mm; jj += 4) {
            int s0 = __shfl(idxv, jj + 0);
            int s1 = __shfl(idxv, jj + 1);
            int s2 = __shfl(idxv, jj + 2);
            int s3 = __shfl(idxv, jj + 3);
            if (lane < NCLS) {
                float t0 = T[(size_t)s0 * NCLS + lane];
                float t1 = T[(size_t)s1 * NCLS + lane];
                float t2 = T[(size_t)s2 * NCLS + lane];
                float t3 = T[(size_t)s3 * NCLS + lane];
                acc += t0 + t1 + t2 + t3;
            }
        }
        for (; jj < mm; ++jj) {
            int s = __shfl(idxv, jj);
            if (lane < NCLS) acc += T[(size_t)s * NCLS + lane];
        }
    }

    float l = (lane < NCLS) ? (acc * di + bf2f(bias[lane])) : -INFINITY;
    float mx = l;
#pragma unroll
    for (int o = 32; o > 0; o >>= 1) mx = fmaxf(mx, __shfl_xor(mx, o));
    float e = (lane < NCLS) ? __expf(l - mx) : 0.f;
    float sum = e;
#pragma unroll
    for (int o = 32; o > 0; o >>= 1) sum += __shfl_xor(sum, o);
    float ls = l - mx - __logf(sum);
    if (lane < NCLS) {
        size_t i0 = (size_t)node * NCLS + lane;
        size_t i1 = (size_t)N_NODES * NCLS + i0;
        if (flags[0]) {
            ((float*)out)[i0] = ls;
            ((float*)out)[i1] = l;
        } else {
            ((ushort*)out)[i0] = f2bf(ls);
            ((ushort*)out)[i1] = f2bf(l);
        }
    }
}

// ---------------- host ----------------

static inline size_t alup(size_t x) { return (x + 255) & ~(size_t)255; }

extern "C" void kernel_launch(void* const* d_in, const int* in_sizes, int n_in,
                              void* d_out, int out_size, void* d_ws, size_t ws_size,
                              hipStream_t stream) {
    char* w = (char*)d_ws;
    int* flags   = (int*)w;           w += alup(16);
    float* dinv  = (float*)w;         w += alup(N_NODES * 4);
    int* cnt     = (int*)w;           w += alup(N_NODES * 4);
    int* offs    = (int*)w;           w += alup(N_NODES * 4);
    int* woff    = (int*)w;           w += alup(N_NODES * 4);
    int* src32   = (int*)w;           w += alup(N_EDGES * 4);
    int* dst32   = (int*)w;           w += alup(N_EDGES * 4);
    int* csr     = (int*)w;           w += alup(N_EDGES * 4);
    ushort* xb   = (ushort*)w;        w += alup((size_t)N_NODES * HDIM * 2);
    ushort* wb[5]; ushort* bb[5];
    for (int l = 0; l < 5; ++l) {
        int wn = (l < 4) ? HDIM * HDIM : HDIM * NCLS;
        int bn = (l < 4) ? HDIM : NCLS;
        wb[l] = (ushort*)w; w += alup((size_t)wn * 2);
        bb[l] = (ushort*)w; w += alup((size_t)bn * 2);
    }
    ushort* tbuf = (ushort*)w;        w += alup((size_t)(N_NODES + 16) * HDIM * 2);
    ushort* hbuf = (ushort*)w;        w += alup((size_t)(N_NODES + 16) * HDIM * 2);
    float* t5    = (float*)w;         w += alup((size_t)N_NODES * NCLS * 4);

    // degree counters must be zero before prep's fused count
    (void)hipMemsetAsync(cnt, 0, N_NODES * 4, stream);

    PrepArgs pa;
    pa.x = d_in[0];
    pa.ei = d_in[1];
    int sizes[10] = { HDIM * HDIM, HDIM, HDIM * HDIM, HDIM, HDIM * HDIM, HDIM,
                      HDIM * HDIM, HDIM, HDIM * NCLS, NCLS };
    int run = 0;
    for (int t = 0; t < 10; ++t) {
        pa.wsrc[t] = d_in[2 + t];
        pa.wdst[t] = (t & 1) ? bb[t >> 1] : wb[t >> 1];
        pa.woffs[t] = run;
        run += sizes[t];
    }
    pa.woffs[10] = run;  // == WTOT
    pa.xb = xb; pa.src32 = src32; pa.dst32 = dst32; pa.cnt = cnt;
    pa.tbuf = tbuf; pa.hbuf = hbuf; pa.flags = flags;

    prep_kernel<<<PREP_TOTAL, 256, 0, stream>>>(pa);
    scan_dinv_kernel<<<1, 1024, 0, stream>>>(cnt, offs, woff, dinv);
    fillgemm_kernel<<<FG_TOTAL, 256, 0, stream>>>(src32, dst32, woff, csr,
                                                  xb, wb[0], dinv, tbuf);

    agg256_kernel<<<AGG_BLKS, 256, 0, stream>>>(tbuf, csr, offs, cnt, dinv, bb[0], hbuf);
    for (int l = 1; l < 4; ++l) {
        gemm256_kernel<<<dim3(8, 78), 256, 0, stream>>>(hbuf, wb[l], dinv, tbuf);
        agg256_kernel<<<AGG_BLKS, 256, 0, stream>>>(tbuf, csr, offs, cnt, dinv, bb[l], hbuf);
    }
    gemm40_kernel<<<dim3(3, 80), 256, 0, stream>>>(hbuf, wb[4], dinv, t5);
    aggsoft_kernel<<<2500, 256, 0, stream>>>(t5, csr, offs, cnt, dinv, bb[4], d_out, flags);
}

// Round 15
// 263.754 us; speedup vs baseline: 1.0309x; 1.0309x over previous
//
#include <hip/hip_runtime.h>
#include <hip/hip_bf16.h>

#define N_NODES 10000
#define N_EDGES 320000
#define HDIM    256
#define NCLS    40
#define WTOT    273448

typedef __attribute__((ext_vector_type(8))) short short8;
typedef __attribute__((ext_vector_type(4))) float floatx4;
typedef unsigned long long ull;
typedef unsigned short ushort;

__device__ __forceinline__ float bf2f(ushort u) {
    union { unsigned int i; float f; } v; v.i = ((unsigned int)u) << 16; return v.f;
}
__device__ __forceinline__ ushort f2bf(float f) {
    __hip_bfloat16 h = __float2bfloat16(f);
    return *reinterpret_cast<ushort*>(&h);
}

// Per-block dtype detection: flags computed from first 64 elements.
__device__ __forceinline__ void detect_flags(const void* x, const void* ei,
                                             int* sflags) {
    const int tid = threadIdx.x;
    if (tid < 64) {
        const ushort* u = (const ushort*)x;
        int e = (u[2 * tid] >> 7) & 0xFF;
        ull badmask = __ballot(e < 100 || e > 140);
        const int* ii = (const int*)ei;
        ull oddnz = __ballot(ii[2 * tid + 1] != 0);
        if (tid == 0) {
            sflags[0] = (__popcll(badmask) >= 8) ? 1 : 0;
            sflags[1] = (oddnz == 0) ? 1 : 0;
        }
    }
    __syncthreads();
}

// ---------------- fused prep: detect + x/W convert + edge decode + count ----------------

struct PrepArgs {
    const void* x;
    const void* ei;
    const void* wsrc[10];
    ushort* wdst[10];
    int woffs[11];
    ushort* xb;
    int* src32;
    int* dst32;
    int* cnt;       // pre-zeroed by hipMemsetAsync
    ushort* tbuf;
    ushort* hbuf;
    int* flags;
};

#define PREP_XB 2500
#define PREP_WB 1069
#define PREP_EB 1250
#define PREP_TOTAL (PREP_XB + PREP_WB + PREP_EB + 1)

__global__ __launch_bounds__(256)
void prep_kernel(PrepArgs a) {
    __shared__ int sflags[2];
    detect_flags(a.x, a.ei, sflags);
    const int f32 = sflags[0];
    const int b = blockIdx.x;

    if (b < PREP_XB) {
        int i4 = b * 256 + threadIdx.x;   // 2500*256 == N*H/4 exactly
        if (f32) {
            float4 v = ((const float4*)a.x)[i4];
            ull p = (ull)f2bf(v.x) | ((ull)f2bf(v.y) << 16) |
                    ((ull)f2bf(v.z) << 32) | ((ull)f2bf(v.w) << 48);
            ((ull*)a.xb)[i4] = p;
        } else {
            ((ull*)a.xb)[i4] = ((const ull*)a.x)[i4];
        }
    } else if (b < PREP_XB + PREP_WB) {
        int i = (b - PREP_XB) * 256 + threadIdx.x;
        if (i < WTOT) {
            int t = 0;
#pragma unroll
            for (int k = 1; k < 10; ++k) t += (i >= a.woffs[k]);
            int local = i - a.woffs[t];
            ushort v;
            if (f32) v = f2bf(((const float*)a.wsrc[t])[local]);
            else     v = ((const ushort*)a.wsrc[t])[local];
            a.wdst[t][local] = v;
        }
    } else if (b < PREP_XB + PREP_WB + PREP_EB) {
        int e = (b - PREP_XB - PREP_WB) * 256 + threadIdx.x;  // exact
        const int* ii = (const int*)a.ei;
        int s, d;
        if (sflags[1]) { s = ii[2 * e]; d = ii[2 * (N_EDGES + e)]; }
        else           { s = ii[e];     d = ii[N_EDGES + e]; }
        s = ((unsigned)s < N_NODES) ? s : 0;
        d = ((unsigned)d < N_NODES) ? d : 0;
        a.src32[e] = s;
        a.dst32[e] = d;
        atomicAdd(&a.cnt[d], 1);
    } else {
        int t = threadIdx.x;
        if (t < 64)       ((ull*)(a.tbuf + (size_t)N_NODES * 256))[t] = 0;
        else if (t < 128) ((ull*)(a.hbuf + (size_t)N_NODES * 256))[t - 64] = 0;
        if (t == 0) { a.flags[0] = sflags[0]; a.flags[1] = sflags[1]; }
    }
}

// ---------------- scan + dinv (1 block, wave-shuffle scan, 2 barriers) ----------------

__global__ __launch_bounds__(1024)
void scan_dinv_kernel(const int* __restrict__ cnt, int* __restrict__ offs,
                      int* __restrict__ woff, float* __restrict__ dinv) {
    __shared__ int wsum[16];
    const int t = threadIdx.x;
    const int lane = t & 63;
    const int wv = t >> 6;
    const int base = t * 10;            // 1024*10 = 10240 >= N_NODES

    int c[10];
    int s = 0;
#pragma unroll
    for (int j = 0; j < 10; ++j) {
        int i = base + j;
        c[j] = (i < N_NODES) ? cnt[i] : 0;
        s += c[j];
    }

    int inc = s;
#pragma unroll
    for (int o = 1; o < 64; o <<= 1) {
        int v = __shfl_up(inc, o);
        if (lane >= o) inc += v;
    }
    if (lane == 63) wsum[wv] = inc;
    __syncthreads();

    if (wv == 0 && lane < 16) {
        int w = wsum[lane];
        int wi = w;
#pragma unroll
        for (int o = 1; o < 16; o <<= 1) {
            int v = __shfl_up(wi, o);
            if (lane >= o) wi += v;
        }
        wsum[lane] = wi - w;
    }
    __syncthreads();

    int run = wsum[wv] + (inc - s);
#pragma unroll
    for (int j = 0; j < 10; ++j) {
        int i = base + j;
        if (i < N_NODES) {
            offs[i] = run;
            woff[i] = run;
            dinv[i] = rsqrtf((float)c[j] + 1.0f);
            run += c[j];
        }
    }
}

// ---------------- fused CSR-fill + GEMM layer 1 ----------------

#define FILL_BLKS 1250
#define GEMM1_YT  78
#define FG_TOTAL  (FILL_BLKS + 8 * GEMM1_YT)

__global__ __launch_bounds__(256)
void fillgemm_kernel(const int* __restrict__ src, const int* __restrict__ dst,
                     int* __restrict__ woff, int* __restrict__ csr,
                     const ushort* __restrict__ A, const ushort* __restrict__ W,
                     const float* __restrict__ dinv, ushort* __restrict__ T) {
    const int b = blockIdx.x;
    if (b < FILL_BLKS) {
        int e = b * 256 + threadIdx.x;
        int d = dst[e];
        int p = atomicAdd(&woff[d], 1);
        csr[p] = src[e];
        return;
    }
    const int g = b - FILL_BLKS;
    const int lane = threadIdx.x & 63;
    const int wave = threadIdx.x >> 6;
    const int m = lane & 15;
    const int quad = lane >> 4;
    const int c0 = (g & 7) * 32;
    const int by = g >> 3;

    short8 bfrag[2][8];
#pragma unroll
    for (int t = 0; t < 2; ++t)
#pragma unroll
        for (int s = 0; s < 8; ++s)
#pragma unroll
            for (int j = 0; j < 8; ++j)
                bfrag[t][s][j] = (short)W[(size_t)(s * 32 + quad * 8 + j) * 256 + c0 + t * 16 + m];

    const int step = GEMM1_YT * 4;
    for (int rt = by * 4 + wave; rt < N_NODES / 16; rt += step) {
        const int r0 = rt * 16;
        floatx4 acc0 = {0.f, 0.f, 0.f, 0.f};
        floatx4 acc1 = {0.f, 0.f, 0.f, 0.f};
        const ushort* arow = A + (size_t)(r0 + m) * 256 + quad * 8;
#pragma unroll
        for (int s = 0; s < 8; ++s) {
            short8 af = *(const short8*)(arow + s * 32);
            acc0 = __builtin_amdgcn_mfma_f32_16x16x32_bf16(af, bfrag[0][s], acc0, 0, 0, 0);
            acc1 = __builtin_amdgcn_mfma_f32_16x16x32_bf16(af, bfrag[1][s], acc1, 0, 0, 0);
        }
#pragma unroll
        for (int r = 0; r < 4; ++r) {
            int row = r0 + quad * 4 + r;
            float di = dinv[row];
            T[(size_t)row * 256 + c0 + m]      = f2bf(acc0[r] * di);
            T[(size_t)row * 256 + c0 + 16 + m] = f2bf(acc1[r] * di);
        }
    }
}

// ---------------- GEMM 256-wide (layers 2-4), grid (8, 78) ----------------

__global__ __launch_bounds__(256)
void gemm256_kernel(const ushort* __restrict__ A, const ushort* __restrict__ W,
                    const float* __restrict__ dinv, ushort* __restrict__ T) {
    const int lane = threadIdx.x & 63;
    const int wave = threadIdx.x >> 6;
    const int m = lane & 15;
    const int quad = lane >> 4;
    const int c0 = blockIdx.x * 32;

    short8 bfrag[2][8];
#pragma unroll
    for (int t = 0; t < 2; ++t)
#pragma unroll
        for (int s = 0; s < 8; ++s)
#pragma unroll
            for (int j = 0; j < 8; ++j)
                bfrag[t][s][j] = (short)W[(size_t)(s * 32 + quad * 8 + j) * 256 + c0 + t * 16 + m];

    const int step = gridDim.y * 4;
    for (int rt = blockIdx.y * 4 + wave; rt < N_NODES / 16; rt += step) {
        const int r0 = rt * 16;
        floatx4 acc0 = {0.f, 0.f, 0.f, 0.f};
        floatx4 acc1 = {0.f, 0.f, 0.f, 0.f};
        const ushort* arow = A + (size_t)(r0 + m) * 256 + quad * 8;
#pragma unroll
        for (int s = 0; s < 8; ++s) {
            short8 af = *(const short8*)(arow + s * 32);
            acc0 = __builtin_amdgcn_mfma_f32_16x16x32_bf16(af, bfrag[0][s], acc0, 0, 0, 0);
            acc1 = __builtin_amdgcn_mfma_f32_16x16x32_bf16(af, bfrag[1][s], acc1, 0, 0, 0);
        }
#pragma unroll
        for (int r = 0; r < 4; ++r) {
            int row = r0 + quad * 4 + r;
            float di = dinv[row];
            T[(size_t)row * 256 + c0 + m]      = f2bf(acc0[r] * di);
            T[(size_t)row * 256 + c0 + 16 + m] = f2bf(acc1[r] * di);
        }
    }
}

// ---------------- GEMM 40-wide -> fp32 t5, grid (3, 80) ----------------

__global__ __launch_bounds__(256)
void gemm40_kernel(const ushort* __restrict__ A, const ushort* __restrict__ W,
                   const float* __restrict__ dinv, float* __restrict__ T) {
    const int lane = threadIdx.x & 63;
    const int wave = threadIdx.x >> 6;
    const int m = lane & 15;
    const int quad = lane >> 4;
    const int col = blockIdx.x * 16 + m;
    const bool colok = col < NCLS;

    short8 bfrag[8];
#pragma unroll
    for (int s = 0; s < 8; ++s)
#pragma unroll
        for (int j = 0; j < 8; ++j)
            bfrag[s][j] = colok ? (short)W[(size_t)(s * 32 + quad * 8 + j) * NCLS + col] : (short)0;

    const int step = gridDim.y * 4;
    for (int rt = blockIdx.y * 4 + wave; rt < N_NODES / 16; rt += step) {
        const int r0 = rt * 16;
        floatx4 acc = {0.f, 0.f, 0.f, 0.f};
        const ushort* arow = A + (size_t)(r0 + m) * 256 + quad * 8;
#pragma unroll
        for (int s = 0; s < 8; ++s) {
            short8 af = *(const short8*)(arow + s * 32);
            acc = __builtin_amdgcn_mfma_f32_16x16x32_bf16(af, bfrag[s], acc, 0, 0, 0);
        }
        if (colok) {
#pragma unroll
            for (int r = 0; r < 4; ++r) {
                int row = r0 + quad * 4 + r;
                T[(size_t)row * NCLS + col] = acc[r] * dinv[row];
            }
        }
    }
}

// ---------------- Aggregation 256-wide (R5 baseline) ----------------

__device__ __forceinline__ void accum16(float* acc, int4 r) {
    int d[4] = {r.x, r.y, r.z, r.w};
#pragma unroll
    for (int k = 0; k < 4; ++k) {
        union { int i; float f; } lo, hi;
        lo.i = d[k] << 16;
        hi.i = d[k] & 0xffff0000;
        acc[2 * k]     += lo.f;
        acc[2 * k + 1] += hi.f;
    }
}

__global__ __launch_bounds__(256)
void agg256_kernel(const ushort* __restrict__ T,
                   const int* __restrict__ csr, const int* __restrict__ offs,
                   const int* __restrict__ cnt, const float* __restrict__ dinv,
                   const ushort* __restrict__ bias,
                   ushort* __restrict__ H) {
    const int node = blockIdx.x * 4 + (threadIdx.x >> 6);
    const int lane = threadIdx.x & 63;
    const int half = lane >> 5;
    const int q = lane & 31;
    const int start = offs[node];
    const int count = cnt[node];
    const float di = dinv[node];

    float acc[8];
    {
        int sinit = half ? N_NODES : node;
        int4 r = *(const int4*)(T + (size_t)sinit * 256 + q * 8);
#pragma unroll
        for (int k = 0; k < 4; ++k) {
            union { int i; float f; } lo, hi;
            int d = (&r.x)[k];
            lo.i = d << 16; hi.i = d & 0xffff0000;
            acc[2 * k] = lo.f; acc[2 * k + 1] = hi.f;
        }
    }

    for (int bj = 0; bj < count; bj += 64) {
        int mrem = count - bj;
        int mm = mrem < 64 ? mrem : 64;
        int idxv = (lane < mm) ? csr[start + bj + lane] : N_NODES;
        int j2 = 0;
        for (; j2 + 8 <= mm; j2 += 8) {
            int s0 = __shfl(idxv, j2 + half);
            int s1 = __shfl(idxv, j2 + 2 + half);
            int s2 = __shfl(idxv, j2 + 4 + half);
            int s3 = __shfl(idxv, j2 + 6 + half);
            int4 r0 = *(const int4*)(T + (size_t)s0 * 256 + q * 8);
            int4 r1 = *(const int4*)(T + (size_t)s1 * 256 + q * 8);
            int4 r2 = *(const int4*)(T + (size_t)s2 * 256 + q * 8);
            int4 r3 = *(const int4*)(T + (size_t)s3 * 256 + q * 8);
            accum16(acc, r0); accum16(acc, r1); accum16(acc, r2); accum16(acc, r3);
        }
        for (; j2 < mm; j2 += 2) {
            int s = __shfl(idxv, j2 + half);
            int4 r = *(const int4*)(T + (size_t)s * 256 + q * 8);
            accum16(acc, r);
        }
    }

#pragma unroll
    for (int i = 0; i < 8; ++i) acc[i] += __shfl_xor(acc[i], 32);

    if (half == 0) {
        int4 bv = *(const int4*)(bias + q * 8);
        int out_d[4];
#pragma unroll
        for (int k = 0; k < 4; ++k) {
            union { int i; float f; } lo, hi;
            int d = (&bv.x)[k];
            lo.i = d << 16; hi.i = d & 0xffff0000;
            float v0 = fmaxf(acc[2 * k] * di + lo.f, 0.f);
            float v1 = fmaxf(acc[2 * k + 1] * di + hi.f, 0.f);
            out_d[k] = (int)f2bf(v0) | ((int)f2bf(v1) << 16);
        }
        *(int4*)(H + (size_t)node * 256 + q * 8) = *(int4*)out_d;
    }
}

// ---------------- Aggregation 40-wide + log_softmax + output ----------------

__global__ __launch_bounds__(256)
void aggsoft_kernel(const float* __restrict__ T,
                    const int* __restrict__ csr, const int* __restrict__ offs,
                    const int* __restrict__ cnt, const float* __restrict__ dinv,
                    const ushort* __restrict__ bias,
                    void* __restrict__ out, const int* __restrict__ flags) {
    const int node = blockIdx.x * 4 + (threadIdx.x >> 6);
    const int lane = threadIdx.x & 63;
    const int start = offs[node];
    const int count = cnt[node];
    const float di = dinv[node];

    float acc = (lane < NCLS) ? T[(size_t)node * NCLS + lane] : 0.f;
    for (int bj = 0; bj < count; bj += 64) {
        int mrem = count - bj;
        int mm = mrem < 64 ? mrem : 64;
        int idxv = (lane < mm) ? csr[start + bj + lane] : 0;
        int jj = 0;
        for (; jj + 4 <= mm; jj += 4) {
            int s0 = __shfl(idxv, jj + 0);
            int s1 = __shfl(idxv, jj + 1);
            int s2 = __shfl(idxv, jj + 2);
            int s3 = __shfl(idxv, jj + 3);
            if (lane < NCLS) {
                float t0 = T[(size_t)s0 * NCLS + lane];
                float t1 = T[(size_t)s1 * NCLS + lane];
                float t2 = T[(size_t)s2 * NCLS + lane];
                float t3 = T[(size_t)s3 * NCLS + lane];
                acc += t0 + t1 + t2 + t3;
            }
        }
        for (; jj < mm; ++jj) {
            int s = __shfl(idxv, jj);
            if (lane < NCLS) acc += T[(size_t)s * NCLS + lane];
        }
    }

    float l = (lane < NCLS) ? (acc * di + bf2f(bias[lane])) : -INFINITY;
    float mx = l;
#pragma unroll
    for (int o = 32; o > 0; o >>= 1) mx = fmaxf(mx, __shfl_xor(mx, o));
    float e = (lane < NCLS) ? __expf(l - mx) : 0.f;
    float sum = e;
#pragma unroll
    for (int o = 32; o > 0; o >>= 1) sum += __shfl_xor(sum, o);
    float ls = l - mx - __logf(sum);
    if (lane < NCLS) {
        size_t i0 = (size_t)node * NCLS + lane;
        size_t i1 = (size_t)N_NODES * NCLS + i0;
        if (flags[0]) {
            ((float*)out)[i0] = ls;
            ((float*)out)[i1] = l;
        } else {
            ((ushort*)out)[i0] = f2bf(ls);
            ((ushort*)out)[i1] = f2bf(l);
        }
    }
}

// ---------------- host ----------------

static inline size_t alup(size_t x) { return (x + 255) & ~(size_t)255; }

extern "C" void kernel_launch(void* const* d_in, const int* in_sizes, int n_in,
                              void* d_out, int out_size, void* d_ws, size_t ws_size,
                              hipStream_t stream) {
    char* w = (char*)d_ws;
    int* flags   = (int*)w;           w += alup(16);
    float* dinv  = (float*)w;         w += alup(N_NODES * 4);
    int* cnt     = (int*)w;           w += alup(N_NODES * 4);
    int* offs    = (int*)w;           w += alup(N_NODES * 4);
    int* woff    = (int*)w;           w += alup(N_NODES * 4);
    int* src32   = (int*)w;           w += alup(N_EDGES * 4);
    int* dst32   = (int*)w;           w += alup(N_EDGES * 4);
    int* csr     = (int*)w;           w += alup(N_EDGES * 4);
    ushort* xb   = (ushort*)w;        w += alup((size_t)N_NODES * HDIM * 2);
    ushort* wb[5]; ushort* bb[5];
    for (int l = 0; l < 5; ++l) {
        int wn = (l < 4) ? HDIM * HDIM : HDIM * NCLS;
        int bn = (l < 4) ? HDIM : NCLS;
        wb[l] = (ushort*)w; w += alup((size_t)wn * 2);
        bb[l] = (ushort*)w; w += alup((size_t)bn * 2);
    }
    ushort* tbuf = (ushort*)w;        w += alup((size_t)(N_NODES + 16) * HDIM * 2);
    ushort* hbuf = (ushort*)w;        w += alup((size_t)(N_NODES + 16) * HDIM * 2);
    float* t5    = (float*)w;         w += alup((size_t)N_NODES * NCLS * 4);

    // degree counters must be zero before prep's fused count
    (void)hipMemsetAsync(cnt, 0, N_NODES * 4, stream);

    PrepArgs pa;
    pa.x = d_in[0];
    pa.ei = d_in[1];
    int sizes[10] = { HDIM * HDIM, HDIM, HDIM * HDIM, HDIM, HDIM * HDIM, HDIM,
                      HDIM * HDIM, HDIM, HDIM * NCLS, NCLS };
    int run = 0;
    for (int t = 0; t < 10; ++t) {
        pa.wsrc[t] = d_in[2 + t];
        pa.wdst[t] = (t & 1) ? bb[t >> 1] : wb[t >> 1];
        pa.woffs[t] = run;
        run += sizes[t];
    }
    pa.woffs[10] = run;  // == WTOT
    pa.xb = xb; pa.src32 = src32; pa.dst32 = dst32; pa.cnt = cnt;
    pa.tbuf = tbuf; pa.hbuf = hbuf; pa.flags = flags;

    prep_kernel<<<PREP_TOTAL, 256, 0, stream>>>(pa);
    scan_dinv_kernel<<<1, 1024, 0, stream>>>(cnt, offs, woff, dinv);
    fillgemm_kernel<<<FG_TOTAL, 256, 0, stream>>>(src32, dst32, woff, csr,
                                                  xb, wb[0], dinv, tbuf);

    const int aggblk = N_NODES / 4;  // 2500

    agg256_kernel<<<aggblk, 256, 0, stream>>>(tbuf, csr, offs, cnt, dinv, bb[0], hbuf);
    for (int l = 1; l < 4; ++l) {
        gemm256_kernel<<<dim3(8, 78), 256, 0, stream>>>(hbuf, wb[l], dinv, tbuf);
        agg256_kernel<<<aggblk, 256, 0, stream>>>(tbuf, csr, offs, cnt, dinv, bb[l], hbuf);
    }
    gemm40_kernel<<<dim3(3, 80), 256, 0, stream>>>(hbuf, wb[4], dinv, t5);
    aggsoft_kernel<<<2500, 256, 0, stream>>>(t5, csr, offs, cnt, dinv, bb[4], d_out, flags);
}